// Round 1
// baseline (928.664 us; speedup 1.0000x reference)
//
#include <hip/hip_runtime.h>
#include <math.h>
#include <stdint.h>

// Problem constants (from reference)
#define BROWS 4096
#define VCOLS 50257
#define KTOP  64
#define NTH   256
#define CAP   2048                 // LDS candidate buffer (floats)
#define COMPACT_AT (CAP - NTH * 4) // compact when count could overflow next tile (=1024)

// ---------------------------------------------------------------------------
// Bitonic ascending sort of CAP elements in LDS, 256 threads.
// Caller must have synced; ends synced.
__device__ __forceinline__ void bitonic_sort_asc(float* buf) {
    const int tid = threadIdx.x;
    for (int k = 2; k <= CAP; k <<= 1) {
        for (int j = k >> 1; j > 0; j >>= 1) {
            __syncthreads();
            for (int i = tid; i < CAP; i += NTH) {
                const int ixj = i ^ j;
                if (ixj > i) {
                    const float a = buf[i];
                    const float b = buf[ixj];
                    const bool up = ((i & k) == 0);
                    if (up ? (a > b) : (a < b)) { buf[i] = b; buf[ixj] = a; }
                }
            }
        }
    }
    __syncthreads();
}

// Compact candidate buffer to its top-64 (left at s_buf[0..63], ascending),
// set *s_thr = 64th largest, *s_count = 64. Call with all 256 threads, synced.
__device__ __forceinline__ void compact_top64(float* s_buf, int* s_count, float* s_thr) {
    const int tid = threadIdx.x;
    const int cnt = *s_count;  // uniform (post-barrier)
    for (int i = cnt + tid; i < CAP; i += NTH) s_buf[i] = -INFINITY;
    bitonic_sort_asc(s_buf);   // internal barriers cover the fill above
    // top-64 now at [CAP-64, CAP); regions [0,64) and [CAP-64,CAP) are disjoint
    if (tid < KTOP) s_buf[tid] = s_buf[CAP - KTOP + tid];
    if (tid == 0) { *s_count = KTOP; *s_thr = s_buf[CAP - KTOP]; }
    __syncthreads();
}

// Wave-aggregated append of `v` into s_buf when ins. One LDS atomic per wave.
__device__ __forceinline__ void try_insert(bool ins, float v, float* s_buf, int* s_count) {
    const unsigned long long mask = __ballot(ins ? 1 : 0);
    if (mask) {
        const int lane   = threadIdx.x & 63;
        const int leader = __builtin_ctzll(mask);
        const int n      = __popcll(mask);
        int base = 0;
        if (lane == leader) base = atomicAdd(s_count, n);
        base = __shfl(base, leader);
        if (ins) {
            const int pos = base + __popcll(mask & ((1ull << lane) - 1ull));
            if (pos < CAP) s_buf[pos] = v;  // guaranteed by compaction policy
        }
    }
}

// ---------------------------------------------------------------------------
// One block per row: stream the row once, keep running top-64 candidates,
// finish with 65-way label-smoothed CE.
__global__ __launch_bounds__(NTH) void topk_ce_kernel(
        const float* __restrict__ input, const int* __restrict__ target,
        float* __restrict__ per_ex, float* __restrict__ out_atomic) {
    __shared__ float s_buf[CAP];
    __shared__ int   s_count;
    __shared__ float s_thr;

    const int row = blockIdx.x;
    const int tid = threadIdx.x;
    const float* rowp = input + (size_t)row * (size_t)VCOLS;
    const int tgt = target[row];

    if (tid == 0) { s_count = 0; s_thr = -INFINITY; }
    __syncthreads();
    float thr = -INFINITY;

    // Rows are only 4B-aligned (V % 4 == 1): scalar prologue up to 16B boundary.
    const int pad = (int)((4u - ((((uintptr_t)rowp) >> 2) & 3u)) & 3u);
    if (tid < 64) {  // wave 0 handles <=3 prologue elements
        const float v = (tid < pad) ? rowp[tid] : -INFINITY;
        const bool ins = (tid < pad) && (v > thr) && (tid != tgt);
        try_insert(ins, v, s_buf, &s_count);
    }

    const int nvec = (VCOLS - pad) >> 2;
    const float4* vp = (const float4*)(rowp + pad);
    const int ntiles = (nvec + NTH - 1) / NTH;

    for (int t = 0; t < ntiles; ++t) {
        const int vi = t * NTH + tid;
        if (vi < nvec) {
            const float4 v4 = vp[vi];
            const int i0 = pad + vi * 4;
            try_insert((v4.x > thr) && (i0     != tgt), v4.x, s_buf, &s_count);
            try_insert((v4.y > thr) && (i0 + 1 != tgt), v4.y, s_buf, &s_count);
            try_insert((v4.z > thr) && (i0 + 2 != tgt), v4.z, s_buf, &s_count);
            try_insert((v4.w > thr) && (i0 + 3 != tgt), v4.w, s_buf, &s_count);
        }
        __syncthreads();
        if (s_count > COMPACT_AT) {          // uniform decision
            compact_top64(s_buf, &s_count, &s_thr);
        }
        __syncthreads();
        thr = s_thr;                          // refresh per-thread threshold
    }

    // scalar tail (<=3 elements)
    const int tail0 = pad + nvec * 4;
    if (tid < 64) {
        const int idx = tail0 + tid;
        const float v = (idx < VCOLS) ? rowp[idx] : -INFINITY;
        const bool ins = (idx < VCOLS) && (v > thr) && (idx != tgt);
        try_insert(ins, v, s_buf, &s_count);
    }
    __syncthreads();
    compact_top64(s_buf, &s_count, &s_thr);   // final: top-64 at s_buf[0..63]

    if (tid == 0) {
        const float tv = rowp[tgt];
        float m = tv;
        for (int i = 0; i < KTOP; ++i) m = fmaxf(m, s_buf[i]);
        float se = expf(tv - m);
        float sv = tv;
        for (int i = 0; i < KTOP; ++i) { se += expf(s_buf[i] - m); sv += s_buf[i]; }
        const float lse = m + logf(se);
        const float pe = lse - 0.9f * tv - 0.1f * (sv * (1.0f / (KTOP + 1)));
        if (per_ex) per_ex[row] = pe;
        else atomicAdd(out_atomic, pe * (1.0f / BROWS));
    }
}

// Deterministic mean of the 4096 per-row losses.
__global__ __launch_bounds__(256) void reduce_mean_kernel(
        const float* __restrict__ per_ex, float* __restrict__ out) {
    __shared__ float s[256];
    const int tid = threadIdx.x;
    float acc = 0.0f;
    for (int i = tid; i < BROWS; i += 256) acc += per_ex[i];
    s[tid] = acc;
    __syncthreads();
    for (int w = 128; w > 0; w >>= 1) {
        if (tid < w) s[tid] += s[tid + w];
        __syncthreads();
    }
    if (tid == 0) out[0] = s[0] * (1.0f / BROWS);
}

extern "C" void kernel_launch(void* const* d_in, const int* in_sizes, int n_in,
                              void* d_out, int out_size, void* d_ws, size_t ws_size,
                              hipStream_t stream) {
    const float* input  = (const float*)d_in[0];
    const int*   target = (const int*)d_in[1];   // jax int64 -> int32 (x64 disabled)
    float* out = (float*)d_out;

    if (ws_size >= BROWS * sizeof(float)) {
        float* per_ex = (float*)d_ws;
        topk_ce_kernel<<<BROWS, NTH, 0, stream>>>(input, target, per_ex, nullptr);
        reduce_mean_kernel<<<1, 256, 0, stream>>>(per_ex, out);
    } else {
        // fallback: atomic accumulation straight into d_out
        hipMemsetAsync(d_out, 0, sizeof(float), stream);
        topk_ce_kernel<<<BROWS, NTH, 0, stream>>>(input, target, nullptr, out);
    }
}

// Round 2
// 179.489 us; speedup vs baseline: 5.1739x; 5.1739x over previous
//
#include <hip/hip_runtime.h>
#include <math.h>
#include <stdint.h>

#define BROWS 4096
#define VCOLS 50257
#define KTOP  64
#define CAP   2048      // per-row LDS candidate buffer (floats)
#define CHECK_AT 1024   // compact when cnt exceeds this (max 1024 inserts per tile)
#define NREG 32         // CAP / 64 lanes

// Order-preserving float->uint key (monotone total order, handles negatives/inf)
__device__ __forceinline__ unsigned f2key(float f) {
    unsigned u = __float_as_uint(f);
    return u ^ ((unsigned)((int)u >> 31) | 0x80000000u);
}
__device__ __forceinline__ float key2f(unsigned k) {
    unsigned u = (k & 0x80000000u) ? (k ^ 0x80000000u) : ~k;
    return __uint_as_float(u);
}

__device__ __forceinline__ int wave_sum_i(int c) {
    #pragma unroll
    for (int d = 1; d < 64; d <<= 1) c += __shfl_xor(c, d);
    return c;
}

// Read CAP floats from LDS as keys into 32 regs/lane; entries >= cnt -> key 0.
// Access pattern: lane-consecutive 16B chunks -> bank-conflict-free.
__device__ __forceinline__ void load_keys(const float* s_buf, unsigned cnt, int lane, unsigned* key) {
    #pragma unroll
    for (int j = 0; j < NREG / 4; ++j) {
        const float4 v = ((const float4*)s_buf)[j * 64 + lane];
        const int base = (j * 64 + lane) * 4;
        key[4*j+0] = (base + 0 < (int)cnt) ? f2key(v.x) : 0u;
        key[4*j+1] = (base + 1 < (int)cnt) ? f2key(v.y) : 0u;
        key[4*j+2] = (base + 2 < (int)cnt) ? f2key(v.z) : 0u;
        key[4*j+3] = (base + 3 < (int)cnt) ? f2key(v.w) : 0u;
    }
}

// Wave-local compaction: keep elements >= (approx) 64th-largest-so-far.
// Guarantees: kept set always contains the true top-64-so-far; cnt >= 64 after.
__device__ __forceinline__ void wave_compact(float* s_buf, unsigned& cnt, float& thr, int lane) {
    __builtin_amdgcn_wave_barrier();
    unsigned key[NREG];
    load_keys(s_buf, cnt, lane, key);
    unsigned kmx = 0u;
    #pragma unroll
    for (int j = 0; j < NREG; ++j) kmx = max(kmx, key[j]);
    #pragma unroll
    for (int d = 1; d < 64; d <<= 1) kmx = max(kmx, (unsigned)__shfl_xor((int)kmx, d));

    unsigned lo = f2key(thr);   // invariant: count(key >= lo) >= 64
    unsigned hi = kmx + 1u;     // count(key >= hi) == 0
    for (int it = 0; it < 12; ++it) {
        if (hi - lo <= 1u) break;
        const unsigned mid = lo + ((hi - lo) >> 1);
        int c = 0;
        #pragma unroll
        for (int j = 0; j < NREG; ++j) c += (key[j] >= mid) ? 1 : 0;
        c = wave_sum_i(c);
        if (c >= KTOP) lo = mid; else hi = mid;
    }
    // pack survivors (key >= lo) to the front via shfl prefix-sum
    int cl = 0; unsigned sm = 0u;
    #pragma unroll
    for (int j = 0; j < NREG; ++j) { const bool s = key[j] >= lo; sm |= (unsigned)s << j; cl += s ? 1 : 0; }
    int incl = cl;
    #pragma unroll
    for (int d = 1; d < 64; d <<= 1) { const int t = __shfl_up(incl, d); if (lane >= d) incl += t; }
    int pos = incl - cl;
    __builtin_amdgcn_wave_barrier();
    #pragma unroll
    for (int j = 0; j < NREG; ++j) if ((sm >> j) & 1u) s_buf[pos++] = key2f(key[j]);
    cnt = (unsigned)__shfl(incl, 63);
    thr = key2f(lo);
    __builtin_amdgcn_wave_barrier();
}

// Exact top-64 + label-smoothed CE over {truth, top64}. Tie-correct via
// boundary multiplicity: K64 = largest key with count(>=K64) >= 64.
__device__ __forceinline__ float wave_final(const float* s_buf, unsigned cnt, float thr, float tv, int lane) {
    __builtin_amdgcn_wave_barrier();
    unsigned key[NREG];
    load_keys(s_buf, cnt, lane, key);
    unsigned kmx = 0u;
    #pragma unroll
    for (int j = 0; j < NREG; ++j) kmx = max(kmx, key[j]);
    #pragma unroll
    for (int d = 1; d < 64; d <<= 1) kmx = max(kmx, (unsigned)__shfl_xor((int)kmx, d));

    unsigned lo = f2key(thr);
    unsigned hi = kmx + 1u;
    while (hi - lo > 1u) {
        const unsigned mid = lo + ((hi - lo) >> 1);
        int c = 0;
        #pragma unroll
        for (int j = 0; j < NREG; ++j) c += (key[j] >= mid) ? 1 : 0;
        c = wave_sum_i(c);
        if (c >= KTOP) lo = mid; else hi = mid;
    }
    const float vmax = key2f(kmx);
    const float m = fmaxf(vmax, tv);
    float se = 0.f, sv = 0.f; int cg = 0;
    #pragma unroll
    for (int j = 0; j < NREG; ++j) {
        if (key[j] > lo) { const float v = key2f(key[j]); se += __expf(v - m); sv += v; ++cg; }
    }
    #pragma unroll
    for (int d = 1; d < 64; d <<= 1) {
        se += __shfl_xor(se, d); sv += __shfl_xor(sv, d); cg += __shfl_xor(cg, d);
    }
    const float v64 = key2f(lo);            // exact 64th largest
    const int nb = KTOP - cg;               // boundary multiplicity (>=1)
    se += (float)nb * __expf(v64 - m);
    sv += (float)nb * v64;
    se += __expf(tv - m);
    const float lse = m + __logf(se);
    return lse - 0.9f * tv - 0.1f * ((sv + tv) * (1.0f / 65.0f));
}

// Ballot-aggregated wave insert; cnt stays a wave-uniform register (no atomics).
__device__ __forceinline__ void ins1(float v, int gi, int tgt, float thr,
                                     float* s_buf, unsigned& cnt, unsigned long long lt) {
    const bool p = (v > thr) && (gi != tgt);
    const unsigned long long mk = __ballot(p ? 1 : 0);
    if (mk) {
        if (p) {
            const unsigned pos = cnt + (unsigned)__popcll(mk & lt);
            if (pos < CAP) s_buf[pos] = v;  // guard only trips on pathological ties
        }
        cnt += (unsigned)__popcll(mk);
    }
}
__device__ __forceinline__ void ins4(const float4 q, int gb, int tgt, float thr,
                                     float* s_buf, unsigned& cnt, unsigned long long lt) {
    ins1(q.x, gb + 0, tgt, thr, s_buf, cnt, lt);
    ins1(q.y, gb + 1, tgt, thr, s_buf, cnt, lt);
    ins1(q.z, gb + 2, tgt, thr, s_buf, cnt, lt);
    ins1(q.w, gb + 3, tgt, thr, s_buf, cnt, lt);
}

// One wave (64-thread block) per row. No __syncthreads, no atomics anywhere.
__global__ __launch_bounds__(64) void topk_ce_kernel(
        const float* __restrict__ input, const int* __restrict__ target,
        float* __restrict__ per_ex, float* __restrict__ out_atomic) {
    __shared__ float s_buf[CAP];
    const int row  = blockIdx.x;
    const int lane = threadIdx.x;
    const float* __restrict__ rowp = input + (size_t)row * (size_t)VCOLS;
    const int tgt = target[row];
    const unsigned long long lt = (1ull << lane) - 1ull;

    unsigned cnt = 0u;
    float thr = -INFINITY;

    // Rows are only 4B-aligned (V % 4 == 1): scalar prologue to 16B boundary.
    const int pad = (int)((4u - ((((uintptr_t)rowp) >> 2) & 3u)) & 3u);
    {
        const float v = (lane < pad) ? rowp[lane] : 0.f;
        const bool p = (lane < pad) && (lane != tgt);
        const unsigned long long mk = __ballot(p ? 1 : 0);
        if (p) s_buf[cnt + __popcll(mk & lt)] = v;
        cnt += (unsigned)__popcll(mk);
    }

    const int nvec  = (VCOLS - pad) >> 2;
    const int ntail = (VCOLS - pad) & 3;
    const float4* __restrict__ vp = (const float4*)(rowp + pad);
    const int ntf = nvec >> 8;   // full tiles: 256 quads = 1024 elems

    for (int t = 0; t < ntf; ++t) {
        const int b0 = t * 256 + lane;
        const float4 a = vp[b0];
        const float4 b = vp[b0 + 64];
        const float4 c = vp[b0 + 128];
        const float4 d = vp[b0 + 192];
        const float mA = fmaxf(fmaxf(a.x, a.y), fmaxf(a.z, a.w));
        const float mB = fmaxf(fmaxf(b.x, b.y), fmaxf(b.z, b.w));
        const float mC = fmaxf(fmaxf(c.x, c.y), fmaxf(c.z, c.w));
        const float mD = fmaxf(fmaxf(d.x, d.y), fmaxf(d.z, d.w));
        const float m16 = fmaxf(fmaxf(mA, mB), fmaxf(mC, mD));
        if (__ballot((m16 > thr) ? 1 : 0)) {   // wave-uniform rare path
            ins4(a, pad + 4 * b0,         tgt, thr, s_buf, cnt, lt);
            ins4(b, pad + 4 * (b0 + 64),  tgt, thr, s_buf, cnt, lt);
            ins4(c, pad + 4 * (b0 + 128), tgt, thr, s_buf, cnt, lt);
            ins4(d, pad + 4 * (b0 + 192), tgt, thr, s_buf, cnt, lt);
        }
        if (cnt > CHECK_AT) wave_compact(s_buf, cnt, thr, lane);
    }

    // remainder quads (< 256), masked, uniform trip count
    for (int k0 = ntf * 256; k0 < nvec; k0 += 64) {
        const int idx = k0 + lane;
        float4 a;
        if (idx < nvec) a = vp[idx];
        else { a.x = a.y = a.z = a.w = -INFINITY; }
        const float mA = fmaxf(fmaxf(a.x, a.y), fmaxf(a.z, a.w));
        if (__ballot((mA > thr) ? 1 : 0))
            ins4(a, pad + 4 * idx, tgt, thr, s_buf, cnt, lt);
        if (cnt > CHECK_AT) wave_compact(s_buf, cnt, thr, lane);
    }

    // scalar tail (<= 3 elems)
    {
        const int idx = pad + 4 * nvec + lane;
        const float v = (lane < ntail) ? rowp[idx] : 0.f;
        const bool p = (lane < ntail) && (v > thr) && (idx != tgt);
        const unsigned long long mk = __ballot(p ? 1 : 0);
        if (p) s_buf[cnt + __popcll(mk & lt)] = v;
        cnt += (unsigned)__popcll(mk);
    }

    const float tv = rowp[tgt];
    const float pe = wave_final(s_buf, cnt, thr, tv, lane);
    if (lane == 0) {
        if (per_ex) per_ex[row] = pe;
        else atomicAdd(out_atomic, pe * (1.0f / BROWS));
    }
}

// Deterministic mean of the 4096 per-row losses.
__global__ __launch_bounds__(256) void reduce_mean_kernel(
        const float* __restrict__ per_ex, float* __restrict__ out) {
    __shared__ float s[256];
    const int tid = threadIdx.x;
    float acc = 0.0f;
    for (int i = tid; i < BROWS; i += 256) acc += per_ex[i];
    s[tid] = acc;
    __syncthreads();
    for (int w = 128; w > 0; w >>= 1) {
        if (tid < w) s[tid] += s[tid + w];
        __syncthreads();
    }
    if (tid == 0) out[0] = s[0] * (1.0f / BROWS);
}

extern "C" void kernel_launch(void* const* d_in, const int* in_sizes, int n_in,
                              void* d_out, int out_size, void* d_ws, size_t ws_size,
                              hipStream_t stream) {
    const float* input  = (const float*)d_in[0];
    const int*   target = (const int*)d_in[1];   // jax int64 -> int32 on device (x64 off)
    float* out = (float*)d_out;

    if (ws_size >= BROWS * sizeof(float)) {
        float* per_ex = (float*)d_ws;
        topk_ce_kernel<<<BROWS, 64, 0, stream>>>(input, target, per_ex, nullptr);
        reduce_mean_kernel<<<1, 256, 0, stream>>>(per_ex, out);
    } else {
        hipMemsetAsync(d_out, 0, sizeof(float), stream);
        topk_ce_kernel<<<BROWS, 64, 0, stream>>>(input, target, nullptr, out);
    }
}